// Round 4
// baseline (852.730 us; speedup 1.0000x reference)
//
#include <hip/hip_runtime.h>
#include <cstdint>

// ---------------------------------------------------------------------------
// Problem constants
// ---------------------------------------------------------------------------
#define Bv   4
#define Nv   1024
#define Cv   1024
#define Hv   16
#define Iv   77
#define IDv  768
#define HDv  64
#define HIDv 4096
#define Sv   (Iv + Nv)      // 1101
#define BIv  (Bv * Iv)      // 308
#define BSv  (Bv * Sv)      // 4404
#define BNv  (Bv * Nv)      // 4096
#define SPADv 1152          // 18*64, zero-padded key dim for V^T

typedef __bf16 bf16x8_t __attribute__((ext_vector_type(8)));
typedef float  f32x4_t  __attribute__((ext_vector_type(4)));
typedef unsigned short us8_t __attribute__((ext_vector_type(8)));

__device__ inline f32x4_t zero4() { f32x4_t z; z[0]=0.f; z[1]=0.f; z[2]=0.f; z[3]=0.f; return z; }

// float -> bf16, round-nearest-even
__device__ inline unsigned short f2bf(float f) {
    unsigned int u = __builtin_bit_cast(unsigned int, f);
    u = (u + 0x7fffu + ((u >> 16) & 1u)) >> 16;
    return (unsigned short)u;
}

__device__ inline float gelu_f(float x) {
    return 0.5f * x * (1.0f + erff(x * 0.70710678118654752440f));
}

// async global(16B/lane) -> LDS  (dest = wave-uniform base + lane*16)
__device__ inline void gload_lds16(const unsigned short* g, unsigned short* l) {
    __builtin_amdgcn_global_load_lds(
        (__attribute__((address_space(1))) void*)(unsigned long long)(const void*)g,
        (__attribute__((address_space(3))) void*)(unsigned long long)(const void*)l,
        16, 0, 0);
}

// ---------------------------------------------------------------------------
// Fused float -> bf16 convert for all 8 weight tensors, with optional
// per-row scaling (gamma folded into weights).  uint4 granules.
// order: qkv | proj(*g1) | fc1 | fc2(*g2) | pfc1 | pfc2(*gate) | ir1 | ir2
// ---------------------------------------------------------------------------
__global__ __launch_bounds__(256) void cvt8_kernel(
        const float* s0, const float* s1, const float* s2, const float* s3,
        const float* s4, const float* s5, const float* s6, const float* s7,
        unsigned short* d0, unsigned short* d1, unsigned short* d2, unsigned short* d3,
        unsigned short* d4, unsigned short* d5, unsigned short* d6, unsigned short* d7,
        const float* g1, const float* g2, const float* gate) {
    long i = (long)blockIdx.x * 256 + threadIdx.x;
    const float* src; unsigned short* dst; long off;
    const float* sptr = nullptr; int K4 = 1;
    if (i < 2097152) {
        if (i < 786432)       { src = s0; dst = d0; off = i; }
        else if (i < 1048576) { src = s1; dst = d1; off = i - 786432;  sptr = g1; K4 = 256; }
        else                  { src = s2; dst = d2; off = i - 1048576; }
    } else if (i < 4194304) {
        if (i < 3145728)      { src = s3; dst = d3; off = i - 2097152; sptr = g2; K4 = 1024; }
        else                  { src = s4; dst = d4; off = i - 3145728; }
    } else {
        if (i < 5242880)      { src = s5; dst = d5; off = i - 4194304; sptr = gate; K4 = 0x7fffffff; }
        else if (i < 5439488) { src = s6; dst = d6; off = i - 5242880; }
        else                  { src = s7; dst = d7; off = i - 5439488; }
    }
    float sc = sptr ? sptr[(int)(off / K4)] : 1.0f;
    float4 v = ((const float4*)src)[off];
    ushort4 o;
    o.x = f2bf(v.x * sc); o.y = f2bf(v.y * sc); o.z = f2bf(v.z * sc); o.w = f2bf(v.w * sc);
    ((ushort4*)dst)[off] = o;
}

// qkvb = [q_bias, 0, v_bias]; bfuse = g2*fc2_b + gate*pfc2_b; projb = g1*proj_b
__global__ __launch_bounds__(256) void bias_prep_kernel(
        const float* __restrict__ qb, const float* __restrict__ vb,
        const float* __restrict__ fc2b, const float* __restrict__ pfc2b,
        const float* __restrict__ projb_in,
        const float* __restrict__ g1, const float* __restrict__ g2,
        const float* __restrict__ gate,
        float* __restrict__ qkvb, float* __restrict__ bfuse,
        float* __restrict__ projb) {
    int i = blockIdx.x * 256 + threadIdx.x;
    if (i < 3 * Cv) {
        float v = 0.f;
        if (i < Cv) v = qb[i];
        else if (i >= 2 * Cv) v = vb[i - 2 * Cv];
        qkvb[i] = v;
    } else if (i < 4 * Cv) {
        int n = i - 3 * Cv;
        bfuse[n] = g2[n] * fc2b[n] + gate[0] * pfc2b[n];
    } else if (i < 5 * Cv) {
        int n = i - 4 * Cv;
        projb[n] = g1[n] * projb_in[n];
    }
}

// scatter kv rows [BI, C] bf16 into cat rows b*S + i
__global__ __launch_bounds__(256) void scatter_kv_kernel(const unsigned short* __restrict__ kv,
                                                         unsigned short* __restrict__ cat) {
    int r = blockIdx.x;
    int b = r / Iv, i = r % Iv;
    const uint2* src = (const uint2*)(kv + (size_t)r * Cv);
    uint2* dst = (uint2*)(cat + (size_t)(b * Sv + i) * Cv);
    dst[threadIdx.x] = src[threadIdx.x];
}

// ---------------------------------------------------------------------------
// LayerNorm (fp32 in) -> bf16 out, one row per block.
// out row index = (r/div)*stride + r%div + off
// ---------------------------------------------------------------------------
__global__ __launch_bounds__(256) void ln_kernel(const float* __restrict__ in,
                                                 const float* __restrict__ w,
                                                 const float* __restrict__ bvec,
                                                 unsigned short* __restrict__ out,
                                                 int cols, float invcols,
                                                 int div_, int stride_, int off_) {
    const int r = blockIdx.x;
    const int tid = threadIdx.x;
    const float* row = in + (size_t)r * cols;
    float s = 0.f, s2 = 0.f;
    for (int c = tid * 4; c < cols; c += 1024) {
        float4 v = *(const float4*)(row + c);
        s  += v.x + v.y + v.z + v.w;
        s2 += v.x * v.x + v.y * v.y + v.z * v.z + v.w * v.w;
    }
#pragma unroll
    for (int o2 = 32; o2 > 0; o2 >>= 1) { s += __shfl_down(s, o2); s2 += __shfl_down(s2, o2); }
    __shared__ float sh[10];
    const int lane = tid & 63, wave = tid >> 6;
    if (lane == 0) { sh[wave] = s; sh[4 + wave] = s2; }
    __syncthreads();
    if (tid == 0) {
        float S1 = sh[0] + sh[1] + sh[2] + sh[3];
        float S2 = sh[4] + sh[5] + sh[6] + sh[7];
        float mean = S1 * invcols;
        float var  = S2 * invcols - mean * mean;
        sh[8] = mean;
        sh[9] = rsqrtf(var + 1e-5f);
    }
    __syncthreads();
    const float mean = sh[8], rstd = sh[9];
    unsigned short* orow = out + (size_t)((r / div_) * stride_ + (r % div_) + off_) * cols;
    for (int c = tid * 4; c < cols; c += 1024) {
        float4 v  = *(const float4*)(row + c);
        float4 wv = *(const float4*)(w + c);
        float4 bv = *(const float4*)(bvec + c);
        ushort4 o;
        o.x = f2bf((v.x - mean) * rstd * wv.x + bv.x);
        o.y = f2bf((v.y - mean) * rstd * wv.y + bv.y);
        o.z = f2bf((v.z - mean) * rstd * wv.z + bv.z);
        o.w = f2bf((v.w - mean) * rstd * wv.w + bv.w);
        *(ushort4*)(orow + c) = o;
    }
}

// ---------------------------------------------------------------------------
// GEMM: O[m,n] = epilogue( sum_k A[m,k]*W[n,k] + bias[n] )
// 128x128 tile, BK=32, double-buffered LDS, one barrier per K-iter.
// MODE 0: out bf16 = v     MODE 1: out bf16 = gelu(v)
// ---------------------------------------------------------------------------
template <int MODE>
__global__ __launch_bounds__(256) void gemm_bf16_kernel(
        const unsigned short* __restrict__ A,
        const unsigned short* __restrict__ W,
        const float* __restrict__ bias,
        unsigned short* __restrict__ outp,
        int M, int N, int K) {
    __shared__ unsigned short As[2][128 * 32];
    __shared__ unsigned short Bs[2][128 * 32];
    const int tid  = threadIdx.x;
    const int lane = tid & 63;
    const int wave = tid >> 6;
    const int m16  = lane & 15;
    const int g4   = lane >> 4;
    const int n0 = blockIdx.x * 128;
    const int m0 = blockIdx.y * 128;
    const int wm = (wave >> 1) * 64;
    const int wn = (wave & 1) * 64;

    const int r0  = tid >> 2;
    const int cc0 = (tid & 3) * 8;
    int am0 = m0 + r0;       if (am0 > M - 1) am0 = M - 1;
    int am1 = m0 + r0 + 64;  if (am1 > M - 1) am1 = M - 1;
    const unsigned short* agp0 = A + (size_t)am0 * K + cc0;
    const unsigned short* agp1 = A + (size_t)am1 * K + cc0;
    const unsigned short* bgp0 = W + (size_t)(n0 + r0) * K + cc0;
    const unsigned short* bgp1 = W + (size_t)(n0 + r0 + 64) * K + cc0;

    f32x4_t acc[4][4];
#pragma unroll
    for (int a = 0; a < 4; ++a)
#pragma unroll
        for (int bb = 0; bb < 4; ++bb) acc[a][bb] = zero4();

    auto stage = [&](int buf) {
        gload_lds16(agp0, &As[buf][wave * 512]);
        gload_lds16(agp1, &As[buf][2048 + wave * 512]);
        gload_lds16(bgp0, &Bs[buf][wave * 512]);
        gload_lds16(bgp1, &Bs[buf][2048 + wave * 512]);
        agp0 += 32; agp1 += 32; bgp0 += 32; bgp1 += 32;
    };

    stage(0);
    const int NIT = K >> 5;
    for (int it = 0; it < NIT; ++it) {
        const int cur = it & 1;
        __syncthreads();
        if (it + 1 < NIT) stage(cur ^ 1);
        bf16x8_t xf[4], wf[4];
#pragma unroll
        for (int bb = 0; bb < 4; ++bb)
            xf[bb] = *(const bf16x8_t*)&As[cur][(wm + bb * 16 + m16) * 32 + g4 * 8];
#pragma unroll
        for (int a = 0; a < 4; ++a)
            wf[a] = *(const bf16x8_t*)&Bs[cur][(wn + a * 16 + m16) * 32 + g4 * 8];
#pragma unroll
        for (int a = 0; a < 4; ++a)
#pragma unroll
            for (int bb = 0; bb < 4; ++bb)
                acc[a][bb] = __builtin_amdgcn_mfma_f32_16x16x32_bf16(wf[a], xf[bb], acc[a][bb], 0, 0, 0);
    }

#pragma unroll
    for (int a = 0; a < 4; ++a) {
        const int cb = n0 + wn + a * 16 + g4 * 4;
        const float4 bv4 = *(const float4*)(bias + cb);
#pragma unroll
        for (int bb = 0; bb < 4; ++bb) {
            const int r = m0 + wm + bb * 16 + m16;
            if (r < M) {
                const size_t idx = (size_t)r * N + cb;
                const float v0 = acc[a][bb][0] + bv4.x;
                const float v1 = acc[a][bb][1] + bv4.y;
                const float v2 = acc[a][bb][2] + bv4.z;
                const float v3 = acc[a][bb][3] + bv4.w;
                if constexpr (MODE == 0) {
                    ushort4 o = {f2bf(v0), f2bf(v1), f2bf(v2), f2bf(v3)};
                    *(ushort4*)(outp + idx) = o;
                } else {
                    ushort4 o = {f2bf(gelu_f(v0)), f2bf(gelu_f(v1)),
                                 f2bf(gelu_f(v2)), f2bf(gelu_f(v3))};
                    *(ushort4*)(outp + idx) = o;
                }
            }
        }
    }
}

// ---------------------------------------------------------------------------
// Split-K GEMM with fp32 atomicAdd epilogue into a pre-zeroed fp32 buffer.
// Virtual K = 2 sources; blockIdx.z < zsplit -> (A1,W1), else (A2,W2);
// k-offset = (z % zsplit) * Kc.  z == 0 additionally adds bias[n] + resid.
// Weights are pre-scaled (gamma folded in), so both sources share the sum.
// ---------------------------------------------------------------------------
__global__ __launch_bounds__(256) void gemm_splitk_kernel(
        const unsigned short* __restrict__ A1,
        const unsigned short* __restrict__ W1,
        const unsigned short* __restrict__ A2,
        const unsigned short* __restrict__ W2,
        const float* __restrict__ bias,
        const float* __restrict__ resid,
        float* __restrict__ out,
        int M, int N, int KA, int Kc, int zsplit) {
    __shared__ unsigned short As[2][128 * 32];
    __shared__ unsigned short Bs[2][128 * 32];
    const int tid  = threadIdx.x;
    const int lane = tid & 63;
    const int wave = tid >> 6;
    const int m16  = lane & 15;
    const int g4   = lane >> 4;
    const int n0 = blockIdx.x * 128;
    const int m0 = blockIdx.y * 128;
    const int z  = blockIdx.z;
    const int wm = (wave >> 1) * 64;
    const int wn = (wave & 1) * 64;

    const unsigned short* A = (z < zsplit) ? A1 : A2;
    const unsigned short* W = (z < zsplit) ? W1 : W2;
    const int k0 = (z % zsplit) * Kc;

    const int r0  = tid >> 2;
    const int cc0 = (tid & 3) * 8;
    int am0 = m0 + r0;       if (am0 > M - 1) am0 = M - 1;
    int am1 = m0 + r0 + 64;  if (am1 > M - 1) am1 = M - 1;
    const unsigned short* agp0 = A + (size_t)am0 * KA + k0 + cc0;
    const unsigned short* agp1 = A + (size_t)am1 * KA + k0 + cc0;
    const unsigned short* bgp0 = W + (size_t)(n0 + r0) * KA + k0 + cc0;
    const unsigned short* bgp1 = W + (size_t)(n0 + r0 + 64) * KA + k0 + cc0;

    f32x4_t acc[4][4];
#pragma unroll
    for (int a = 0; a < 4; ++a)
#pragma unroll
        for (int bb = 0; bb < 4; ++bb) acc[a][bb] = zero4();

    auto stage = [&](int buf) {
        gload_lds16(agp0, &As[buf][wave * 512]);
        gload_lds16(agp1, &As[buf][2048 + wave * 512]);
        gload_lds16(bgp0, &Bs[buf][wave * 512]);
        gload_lds16(bgp1, &Bs[buf][2048 + wave * 512]);
        agp0 += 32; agp1 += 32; bgp0 += 32; bgp1 += 32;
    };

    stage(0);
    const int NIT = Kc >> 5;
    for (int it = 0; it < NIT; ++it) {
        const int cur = it & 1;
        __syncthreads();
        if (it + 1 < NIT) stage(cur ^ 1);
        bf16x8_t xf[4], wf[4];
#pragma unroll
        for (int bb = 0; bb < 4; ++bb)
            xf[bb] = *(const bf16x8_t*)&As[cur][(wm + bb * 16 + m16) * 32 + g4 * 8];
#pragma unroll
        for (int a = 0; a < 4; ++a)
            wf[a] = *(const bf16x8_t*)&Bs[cur][(wn + a * 16 + m16) * 32 + g4 * 8];
#pragma unroll
        for (int a = 0; a < 4; ++a)
#pragma unroll
            for (int bb = 0; bb < 4; ++bb)
                acc[a][bb] = __builtin_amdgcn_mfma_f32_16x16x32_bf16(wf[a], xf[bb], acc[a][bb], 0, 0, 0);
    }

    const bool lead = (z == 0);
#pragma unroll
    for (int a = 0; a < 4; ++a) {
        const int cb = n0 + wn + a * 16 + g4 * 4;
        const float4 bv4 = lead ? *(const float4*)(bias + cb) : float4{0.f, 0.f, 0.f, 0.f};
#pragma unroll
        for (int bb = 0; bb < 4; ++bb) {
            const int r = m0 + wm + bb * 16 + m16;
            if (r < M) {
                const size_t idx = (size_t)r * N + cb;
                float v0 = acc[a][bb][0] + bv4.x;
                float v1 = acc[a][bb][1] + bv4.y;
                float v2 = acc[a][bb][2] + bv4.z;
                float v3 = acc[a][bb][3] + bv4.w;
                if (lead) {
                    float4 res = *(const float4*)(resid + idx);
                    v0 += res.x; v1 += res.y; v2 += res.z; v3 += res.w;
                }
                atomicAdd(out + idx + 0, v0);
                atomicAdd(out + idx + 1, v1);
                atomicAdd(out + idx + 2, v2);
                atomicAdd(out + idx + 3, v3);
            }
        }
    }
}

// ---------------------------------------------------------------------------
// V^T pre-transpose with baked PV key-permutation.
// ---------------------------------------------------------------------------
__global__ __launch_bounds__(256) void vtrans_kernel(const unsigned short* __restrict__ qkv,
                                                     unsigned short* __restrict__ vt) {
    __shared__ unsigned short Vs[64 * 64];
    const int stile = blockIdx.x;   // 0..17
    const int bh = blockIdx.y;
    const int b = bh >> 4, h = bh & 15;
    const int tid = threadIdx.x;
#pragma unroll
    for (int j = 0; j < 2; ++j) {
        int c = j * 256 + tid;
        int r = c >> 3, d8 = (c & 7) * 8;
        int s = stile * 64 + r;
        uint4 v = {0u, 0u, 0u, 0u};
        if (s < Sv) v = *(const uint4*)(qkv + ((size_t)(b * Sv + s) * 3 + 2) * Cv + h * 64 + d8);
        *(uint4*)&Vs[r * 64 + d8] = v;
    }
    __syncthreads();
    const int d  = tid >> 2;
    const int p0 = (tid & 3) * 16;
    unsigned short tmp[16];
#pragma unroll
    for (int e = 0; e < 16; ++e) {
        int p = p0 + e;
        int s_local = (p & 32) + 16 * ((p >> 2) & 1) + 4 * ((p & 31) >> 3) + (p & 3);
        tmp[e] = Vs[s_local * 64 + d];
    }
    unsigned short* dst = vt + ((size_t)bh * 64 + d) * SPADv + stile * 64 + p0;
    *(uint4*)dst       = *(const uint4*)&tmp[0];
    *(uint4*)(dst + 8) = *(const uint4*)&tmp[8];
}

// ---------------------------------------------------------------------------
// Flash attention, S^T formulation.
// ---------------------------------------------------------------------------
__global__ __launch_bounds__(256) void attn_kernel(const unsigned short* __restrict__ qkv,
                                                   const unsigned short* __restrict__ vt,
                                                   unsigned short* __restrict__ o) {
    __shared__ unsigned short Qs[64 * 64];
    __shared__ unsigned short Ks[2][64 * 64];
    __shared__ unsigned short Vts[2][64 * 64];

    const int tid  = threadIdx.x;
    const int lane = tid & 63;
    const int wave = tid >> 6;
    const int m16  = lane & 15;
    const int g4   = lane >> 4;
    const int qt = blockIdx.x;
    const int bh = blockIdx.y;
    const int b = bh >> 4, h = bh & 15;

    const int lr = lane >> 3;
    const int csw = ((lane & 7) ^ lr) * 8;
    const int sw7 = m16 & 7;

#pragma unroll
    for (int j = 0; j < 2; ++j) {
        int r = wave * 16 + j * 8 + lr;
        int s = Iv + qt * 64 + r;
        gload_lds16(qkv + ((size_t)(b * Sv + s) * 3) * Cv + h * 64 + csw,
                    &Qs[(wave * 16 + j * 8) * 64]);
    }

    auto stage_kv = [&](int st, int buf) {
#pragma unroll
        for (int j = 0; j < 2; ++j) {
            int r = wave * 16 + j * 8 + lr;
            int s = st * 64 + r; if (s > Sv - 1) s = Sv - 1;
            gload_lds16(qkv + ((size_t)(b * Sv + s) * 3 + 1) * Cv + h * 64 + csw,
                        &Ks[buf][(wave * 16 + j * 8) * 64]);
            gload_lds16(vt + ((size_t)bh * 64 + r) * SPADv + st * 64 + csw,
                        &Vts[buf][(wave * 16 + j * 8) * 64]);
        }
    };

    f32x4_t oacc[4];
#pragma unroll
    for (int dt = 0; dt < 4; ++dt) oacc[dt] = zero4();
    float m_run = -1e30f, l_run = 0.f;

    stage_kv(0, 0);
    __syncthreads();

    const bf16x8_t qf0 = *(const bf16x8_t*)&Qs[(wave * 16 + m16) * 64 + ((g4 ^ sw7) * 8)];
    const bf16x8_t qf1 = *(const bf16x8_t*)&Qs[(wave * 16 + m16) * 64 + (((4 + g4) ^ sw7) * 8)];

    const int NT = (Sv + 63) / 64;   // 18
    for (int st = 0; st < NT; ++st) {
        const int cur = st & 1;
        if (st + 1 < NT) stage_kv(st + 1, cur ^ 1);

        f32x4_t sc[4];
#pragma unroll
        for (int kt = 0; kt < 4; ++kt) {
            bf16x8_t k0 = *(const bf16x8_t*)&Ks[cur][(kt * 16 + m16) * 64 + ((g4 ^ sw7) * 8)];
            bf16x8_t k1 = *(const bf16x8_t*)&Ks[cur][(kt * 16 + m16) * 64 + (((4 + g4) ^ sw7) * 8)];
            f32x4_t z = zero4();
            z = __builtin_amdgcn_mfma_f32_16x16x32_bf16(k0, qf0, z, 0, 0, 0);
            z = __builtin_amdgcn_mfma_f32_16x16x32_bf16(k1, qf1, z, 0, 0, 0);
            sc[kt] = z;
        }

        float mx = -1e30f;
#pragma unroll
        for (int kt = 0; kt < 4; ++kt)
#pragma unroll
            for (int r = 0; r < 4; ++r) {
                int key = st * 64 + kt * 16 + g4 * 4 + r;
                float v = sc[kt][r] * 0.125f;
                v = (key < Sv) ? v : -1e30f;
                sc[kt][r] = v;
                mx = fmaxf(mx, v);
            }
        mx = fmaxf(mx, __shfl_xor(mx, 16));
        mx = fmaxf(mx, __shfl_xor(mx, 32));
        const float mnew  = fmaxf(m_run, mx);
        const float alpha = __expf(m_run - mnew);
        m_run = mnew;
        float sum = 0.f;
#pragma unroll
        for (int kt = 0; kt < 4; ++kt)
#pragma unroll
            for (int r = 0; r < 4; ++r) {
                float p = __expf(sc[kt][r] - mnew);
                sc[kt][r] = p;
                sum += p;
            }
        sum += __shfl_xor(sum, 16);
        sum += __shfl_xor(sum, 32);
        l_run = l_run * alpha + sum;
#pragma unroll
        for (int dt = 0; dt < 4; ++dt) oacc[dt] *= alpha;

        us8_t pu0, pu1;
#pragma unroll
        for (int j = 0; j < 8; ++j) {
            pu0[j] = f2bf(sc[(j >> 2)][j & 3]);
            pu1[j] = f2bf(sc[2 + (j >> 2)][j & 3]);
        }
        const bf16x8_t pf0 = __builtin_bit_cast(bf16x8_t, pu0);
        const bf16x8_t pf1 = __builtin_bit_cast(bf16x8_t, pu1);

#pragma unroll
        for (int dt = 0; dt < 4; ++dt) {
            bf16x8_t v0 = *(const bf16x8_t*)&Vts[cur][(dt * 16 + m16) * 64 + ((g4 ^ sw7) * 8)];
            bf16x8_t v1 = *(const bf16x8_t*)&Vts[cur][(dt * 16 + m16) * 64 + (((4 + g4) ^ sw7) * 8)];
            oacc[dt] = __builtin_amdgcn_mfma_f32_16x16x32_bf16(v0, pf0, oacc[dt], 0, 0, 0);
            oacc[dt] = __builtin_amdgcn_mfma_f32_16x16x32_bf16(v1, pf1, oacc[dt], 0, 0, 0);
        }
        __syncthreads();
    }

    const float inv = 1.0f / l_run;
    const int q = qt * 64 + wave * 16 + m16;
    const size_t row = (size_t)(b * Nv + q) * Cv + h * 64;
#pragma unroll
    for (int dt = 0; dt < 4; ++dt) {
        ushort4 o4 = {f2bf(oacc[dt][0] * inv), f2bf(oacc[dt][1] * inv),
                      f2bf(oacc[dt][2] * inv), f2bf(oacc[dt][3] * inv)};
        *(ushort4*)&o[row + dt * 16 + g4 * 4] = o4;
    }
}

// ---------------------------------------------------------------------------
// Launcher
// ---------------------------------------------------------------------------
extern "C" void kernel_launch(void* const* d_in, const int* in_sizes, int n_in,
                              void* d_out, int out_size, void* d_ws, size_t ws_size,
                              hipStream_t stream) {
    (void)in_sizes; (void)n_in; (void)out_size; (void)ws_size;
    const float* x       = (const float*)d_in[0];
    const float* instr   = (const float*)d_in[1];
    const float* norm1_w = (const float*)d_in[2];
    const float* norm1_b = (const float*)d_in[3];
    const float* qkv_w   = (const float*)d_in[4];
    const float* q_bias  = (const float*)d_in[5];
    const float* v_bias  = (const float*)d_in[6];
    const float* proj_w  = (const float*)d_in[7];
    const float* proj_b  = (const float*)d_in[8];
    const float* gamma_1 = (const float*)d_in[9];
    const float* gamma_2 = (const float*)d_in[10];
    const float* norm2_w = (const float*)d_in[11];
    const float* norm2_b = (const float*)d_in[12];
    const float* fc1_w   = (const float*)d_in[13];
    const float* fc1_b   = (const float*)d_in[14];
    const float* fc2_w   = (const float*)d_in[15];
    const float* fc2_b   = (const float*)d_in[16];
    const float* pfc1_w  = (const float*)d_in[17];
    const float* pfc1_b  = (const float*)d_in[18];
    const float* pfc2_w  = (const float*)d_in[19];
    const float* pfc2_b  = (const float*)d_in[20];
    const float* gate    = (const float*)d_in[21];
    const float* ir_ln_w = (const float*)d_in[22];
    const float* ir_ln_b = (const float*)d_in[23];
    const float* ir_l1_w = (const float*)d_in[24];
    const float* ir_l1_b = (const float*)d_in[25];
    const float* ir_l2_w = (const float*)d_in[26];
    const float* ir_l2_b = (const float*)d_in[27];
    float* out = (float*)d_out;

    char* ws = (char*)d_ws;
    size_t off = 0;
    auto alloc = [&](size_t bytes) -> char* {
        char* p = ws + off;
        off += (bytes + 255) & ~(size_t)255;
        return p;
    };
    unsigned short* w_qkv  = (unsigned short*)alloc((size_t)3 * Cv * Cv * 2);
    unsigned short* w_proj = (unsigned short*)alloc((size_t)Cv * Cv * 2);   // *g1
    unsigned short* w_fc1  = (unsigned short*)alloc((size_t)HIDv * Cv * 2);
    unsigned short* w_fc2  = (unsigned short*)alloc((size_t)Cv * HIDv * 2); // *g2
    unsigned short* w_pfc1 = (unsigned short*)alloc((size_t)HIDv * Cv * 2);
    unsigned short* w_pfc2 = (unsigned short*)alloc((size_t)Cv * HIDv * 2); // *gate
    unsigned short* w_ir1  = (unsigned short*)alloc((size_t)Cv * IDv * 2);
    unsigned short* w_ir2  = (unsigned short*)alloc((size_t)Cv * Cv * 2);
    float*          qkvb   = (float*)alloc((size_t)3 * Cv * 4);
    float*          bfuse  = (float*)alloc((size_t)Cv * 4);
    float*          projb  = (float*)alloc((size_t)Cv * 4);
    unsigned short* irln   = (unsigned short*)alloc((size_t)BIv * IDv * 2);
    unsigned short* h1     = (unsigned short*)alloc((size_t)BIv * Cv * 2);
    unsigned short* kvtmp  = (unsigned short*)alloc((size_t)BIv * Cv * 2);
    unsigned short* cat    = (unsigned short*)alloc((size_t)BSv * Cv * 2);
    unsigned short* qkvbuf = (unsigned short*)alloc((size_t)BSv * 3 * Cv * 2);
    unsigned short* obuf   = (unsigned short*)alloc((size_t)BNv * Cv * 2);
    float*          x1     = (float*)alloc((size_t)BNv * Cv * 4);
    unsigned short* ybuf   = (unsigned short*)alloc((size_t)BNv * Cv * 2);
    unsigned short* gbuf1  = (unsigned short*)alloc((size_t)BNv * HIDv * 2);
    unsigned short* vt     = gbuf1;   // vt dead before fc1 writes gbuf1
    unsigned short* gbuf2  = cat;     // cat+qkvbuf dead by LN2; 9.0+27.1 MB >= 32 MB

    cvt8_kernel<<<22272, 256, 0, stream>>>(qkv_w, proj_w, fc1_w, fc2_w, pfc1_w, pfc2_w,
                                           ir_l1_w, ir_l2_w,
                                           w_qkv, w_proj, w_fc1, w_fc2, w_pfc1, w_pfc2,
                                           w_ir1, w_ir2,
                                           gamma_1, gamma_2, gate);

    bias_prep_kernel<<<20, 256, 0, stream>>>(q_bias, v_bias, fc2_b, pfc2_b, proj_b,
                                             gamma_1, gamma_2, gate,
                                             qkvb, bfuse, projb);

    // instruct branch: LN -> Linear+GELU -> Linear
    ln_kernel<<<BIv, 256, 0, stream>>>(instr, ir_ln_w, ir_ln_b, irln,
                                       IDv, 1.0f / IDv, 1 << 28, 0, 0);
    // LN1 writes directly into cat rows b*S + I + n
    ln_kernel<<<BNv, 256, 0, stream>>>(x, norm1_w, norm1_b, cat,
                                       Cv, 1.0f / Cv, Nv, Sv, Iv);
    gemm_bf16_kernel<1><<<dim3(Cv / 128, (BIv + 127) / 128), 256, 0, stream>>>(
        irln, w_ir1, ir_l1_b, h1, BIv, Cv, IDv);
    gemm_bf16_kernel<0><<<dim3(Cv / 128, (BIv + 127) / 128), 256, 0, stream>>>(
        h1, w_ir2, ir_l2_b, kvtmp, BIv, Cv, Cv);
    scatter_kv_kernel<<<BIv, 256, 0, stream>>>(kvtmp, cat);

    // QKV projection over cat [BS, C] -> [BS, 3C]
    gemm_bf16_kernel<0><<<dim3(3 * Cv / 128, (BSv + 127) / 128), 256, 0, stream>>>(
        cat, w_qkv, qkvb, qkvbuf, BSv, 3 * Cv, Cv);

    // V^T pre-transpose (permuted), then attention
    vtrans_kernel<<<dim3(18, Bv * Hv), 256, 0, stream>>>(qkvbuf, vt);
    attn_kernel<<<dim3(Nv / 64, Bv * Hv), 256, 0, stream>>>(qkvbuf, vt, obuf);

    // proj + LayerScale residual via split-K=2 atomics:
    // x1 = x + (o @ (g1*proj_w)^T + g1*proj_b)
    hipMemsetAsync(x1, 0, (size_t)BNv * Cv * 4, stream);
    gemm_splitk_kernel<<<dim3(Cv / 128, BNv / 128, 2), 256, 0, stream>>>(
        obuf, w_proj, obuf, w_proj, projb, x, x1, BNv, Cv, Cv, Cv / 2, 2);

    // LN2
    ln_kernel<<<BNv, 256, 0, stream>>>(x1, norm2_w, norm2_b, ybuf,
                                       Cv, 1.0f / Cv, 1 << 28, 0, 0);

    // fc1 / pfc1 (separate, 1024 blocks each, 16 accs -> good occupancy)
    gemm_bf16_kernel<1><<<dim3(HIDv / 128, BNv / 128), 256, 0, stream>>>(
        ybuf, w_fc1, fc1_b, gbuf1, BNv, HIDv, Cv);
    gemm_bf16_kernel<1><<<dim3(HIDv / 128, BNv / 128), 256, 0, stream>>>(
        ybuf, w_pfc1, pfc1_b, gbuf2, BNv, HIDv, Cv);

    // fc2 + pfc2 as ONE virtual-K=8192 split-K=4 GEMM (gamma/gate pre-folded):
    // out = x1 + bfuse + g1@(g2*fc2)^T + g2b@(gate*pfc2)^T
    hipMemsetAsync(out, 0, (size_t)BNv * Cv * 4, stream);
    gemm_splitk_kernel<<<dim3(Cv / 128, BNv / 128, 4), 256, 0, stream>>>(
        gbuf1, w_fc2, gbuf2, w_pfc2, bfuse, x1, out, BNv, Cv, HIDv, HIDv / 2, 2);
}

// Round 5
// 609.419 us; speedup vs baseline: 1.3993x; 1.3993x over previous
//
#include <hip/hip_runtime.h>
#include <cstdint>

// ---------------------------------------------------------------------------
// Problem constants
// ---------------------------------------------------------------------------
#define Bv   4
#define Nv   1024
#define Cv   1024
#define Hv   16
#define Iv   77
#define IDv  768
#define HDv  64
#define HIDv 4096
#define Sv   (Iv + Nv)      // 1101
#define BIv  (Bv * Iv)      // 308
#define BSv  (Bv * Sv)      // 4404
#define BNv  (Bv * Nv)      // 4096
#define SPADv 1152          // 18*64, zero-padded key dim for V^T

typedef __bf16 bf16x8_t __attribute__((ext_vector_type(8)));
typedef float  f32x4_t  __attribute__((ext_vector_type(4)));
typedef unsigned short us8_t __attribute__((ext_vector_type(8)));

__device__ inline f32x4_t zero4() { f32x4_t z; z[0]=0.f; z[1]=0.f; z[2]=0.f; z[3]=0.f; return z; }

// float -> bf16, round-nearest-even
__device__ inline unsigned short f2bf(float f) {
    unsigned int u = __builtin_bit_cast(unsigned int, f);
    u = (u + 0x7fffu + ((u >> 16) & 1u)) >> 16;
    return (unsigned short)u;
}
__device__ inline float bf2f(unsigned short u) {
    return __builtin_bit_cast(float, ((unsigned int)u) << 16);
}

__device__ inline float gelu_f(float x) {
    return 0.5f * x * (1.0f + erff(x * 0.70710678118654752440f));
}

// async global(16B/lane) -> LDS  (dest = wave-uniform base + lane*16)
__device__ inline void gload_lds16(const unsigned short* g, unsigned short* l) {
    __builtin_amdgcn_global_load_lds(
        (__attribute__((address_space(1))) void*)(unsigned long long)(const void*)g,
        (__attribute__((address_space(3))) void*)(unsigned long long)(const void*)l,
        16, 0, 0);
}

// ---------------------------------------------------------------------------
// Fused float -> bf16 convert for all 8 weight tensors, with optional
// per-row scaling (gamma folded into weights).  uint4 granules.
// order: qkv | proj(*g1) | fc1 | fc2(*g2) | pfc1 | pfc2(*gate) | ir1 | ir2
// ---------------------------------------------------------------------------
__global__ __launch_bounds__(256) void cvt8_kernel(
        const float* s0, const float* s1, const float* s2, const float* s3,
        const float* s4, const float* s5, const float* s6, const float* s7,
        unsigned short* d0, unsigned short* d1, unsigned short* d2, unsigned short* d3,
        unsigned short* d4, unsigned short* d5, unsigned short* d6, unsigned short* d7,
        const float* g1, const float* g2, const float* gate) {
    long i = (long)blockIdx.x * 256 + threadIdx.x;
    const float* src; unsigned short* dst; long off;
    const float* sptr = nullptr; int K4 = 1;
    if (i < 2097152) {
        if (i < 786432)       { src = s0; dst = d0; off = i; }
        else if (i < 1048576) { src = s1; dst = d1; off = i - 786432;  sptr = g1; K4 = 256; }
        else                  { src = s2; dst = d2; off = i - 1048576; }
    } else if (i < 4194304) {
        if (i < 3145728)      { src = s3; dst = d3; off = i - 2097152; sptr = g2; K4 = 1024; }
        else                  { src = s4; dst = d4; off = i - 3145728; }
    } else {
        if (i < 5242880)      { src = s5; dst = d5; off = i - 4194304; sptr = gate; K4 = 0x7fffffff; }
        else if (i < 5439488) { src = s6; dst = d6; off = i - 5242880; }
        else                  { src = s7; dst = d7; off = i - 5439488; }
    }
    float sc = sptr ? sptr[(int)(off / K4)] : 1.0f;
    float4 v = ((const float4*)src)[off];
    ushort4 o;
    o.x = f2bf(v.x * sc); o.y = f2bf(v.y * sc); o.z = f2bf(v.z * sc); o.w = f2bf(v.w * sc);
    ((ushort4*)dst)[off] = o;
}

// qkvb = [q_bias, 0, v_bias]; bfuse = g2*fc2_b + gate*pfc2_b; projb = g1*proj_b
__global__ __launch_bounds__(256) void bias_prep_kernel(
        const float* __restrict__ qb, const float* __restrict__ vb,
        const float* __restrict__ fc2b, const float* __restrict__ pfc2b,
        const float* __restrict__ projb_in,
        const float* __restrict__ g1, const float* __restrict__ g2,
        const float* __restrict__ gate,
        float* __restrict__ qkvb, float* __restrict__ bfuse,
        float* __restrict__ projb) {
    int i = blockIdx.x * 256 + threadIdx.x;
    if (i < 3 * Cv) {
        float v = 0.f;
        if (i < Cv) v = qb[i];
        else if (i >= 2 * Cv) v = vb[i - 2 * Cv];
        qkvb[i] = v;
    } else if (i < 4 * Cv) {
        int n = i - 3 * Cv;
        bfuse[n] = g2[n] * fc2b[n] + gate[0] * pfc2b[n];
    } else if (i < 5 * Cv) {
        int n = i - 4 * Cv;
        projb[n] = g1[n] * projb_in[n];
    }
}

// scatter kv rows [BI, C] bf16 into cat rows b*S + i
__global__ __launch_bounds__(256) void scatter_kv_kernel(const unsigned short* __restrict__ kv,
                                                         unsigned short* __restrict__ cat) {
    int r = blockIdx.x;
    int b = r / Iv, i = r % Iv;
    const uint2* src = (const uint2*)(kv + (size_t)r * Cv);
    uint2* dst = (uint2*)(cat + (size_t)(b * Sv + i) * Cv);
    dst[threadIdx.x] = src[threadIdx.x];
}

// ---------------------------------------------------------------------------
// LayerNorm (fp32 in) -> bf16 out, one row per block.
// out row index = (r/div)*stride + r%div + off
// ---------------------------------------------------------------------------
__global__ __launch_bounds__(256) void ln_kernel(const float* __restrict__ in,
                                                 const float* __restrict__ w,
                                                 const float* __restrict__ bvec,
                                                 unsigned short* __restrict__ out,
                                                 int cols, float invcols,
                                                 int div_, int stride_, int off_) {
    const int r = blockIdx.x;
    const int tid = threadIdx.x;
    const float* row = in + (size_t)r * cols;
    float s = 0.f, s2 = 0.f;
    for (int c = tid * 4; c < cols; c += 1024) {
        float4 v = *(const float4*)(row + c);
        s  += v.x + v.y + v.z + v.w;
        s2 += v.x * v.x + v.y * v.y + v.z * v.z + v.w * v.w;
    }
#pragma unroll
    for (int o2 = 32; o2 > 0; o2 >>= 1) { s += __shfl_down(s, o2); s2 += __shfl_down(s2, o2); }
    __shared__ float sh[10];
    const int lane = tid & 63, wave = tid >> 6;
    if (lane == 0) { sh[wave] = s; sh[4 + wave] = s2; }
    __syncthreads();
    if (tid == 0) {
        float S1 = sh[0] + sh[1] + sh[2] + sh[3];
        float S2 = sh[4] + sh[5] + sh[6] + sh[7];
        float mean = S1 * invcols;
        float var  = S2 * invcols - mean * mean;
        sh[8] = mean;
        sh[9] = rsqrtf(var + 1e-5f);
    }
    __syncthreads();
    const float mean = sh[8], rstd = sh[9];
    unsigned short* orow = out + (size_t)((r / div_) * stride_ + (r % div_) + off_) * cols;
    for (int c = tid * 4; c < cols; c += 1024) {
        float4 v  = *(const float4*)(row + c);
        float4 wv = *(const float4*)(w + c);
        float4 bv = *(const float4*)(bvec + c);
        ushort4 o;
        o.x = f2bf((v.x - mean) * rstd * wv.x + bv.x);
        o.y = f2bf((v.y - mean) * rstd * wv.y + bv.y);
        o.z = f2bf((v.z - mean) * rstd * wv.z + bv.z);
        o.w = f2bf((v.w - mean) * rstd * wv.w + bv.w);
        *(ushort4*)(orow + c) = o;
    }
}

// ---------------------------------------------------------------------------
// GEMM: O[m,n] = epilogue( sum_k A[m,k]*W[n,k] + bias[n] )
// 128x128 tile, BK=32, double-buffered LDS, one barrier per K-iter.
// MODE 0: out bf16 = v     MODE 1: out bf16 = gelu(v)
// ---------------------------------------------------------------------------
template <int MODE>
__global__ __launch_bounds__(256) void gemm_bf16_kernel(
        const unsigned short* __restrict__ A,
        const unsigned short* __restrict__ W,
        const float* __restrict__ bias,
        unsigned short* __restrict__ outp,
        int M, int N, int K) {
    __shared__ unsigned short As[2][128 * 32];
    __shared__ unsigned short Bs[2][128 * 32];
    const int tid  = threadIdx.x;
    const int lane = tid & 63;
    const int wave = tid >> 6;
    const int m16  = lane & 15;
    const int g4   = lane >> 4;
    const int n0 = blockIdx.x * 128;
    const int m0 = blockIdx.y * 128;
    const int wm = (wave >> 1) * 64;
    const int wn = (wave & 1) * 64;

    const int r0  = tid >> 2;
    const int cc0 = (tid & 3) * 8;
    int am0 = m0 + r0;       if (am0 > M - 1) am0 = M - 1;
    int am1 = m0 + r0 + 64;  if (am1 > M - 1) am1 = M - 1;
    const unsigned short* agp0 = A + (size_t)am0 * K + cc0;
    const unsigned short* agp1 = A + (size_t)am1 * K + cc0;
    const unsigned short* bgp0 = W + (size_t)(n0 + r0) * K + cc0;
    const unsigned short* bgp1 = W + (size_t)(n0 + r0 + 64) * K + cc0;

    f32x4_t acc[4][4];
#pragma unroll
    for (int a = 0; a < 4; ++a)
#pragma unroll
        for (int bb = 0; bb < 4; ++bb) acc[a][bb] = zero4();

    auto stage = [&](int buf) {
        gload_lds16(agp0, &As[buf][wave * 512]);
        gload_lds16(agp1, &As[buf][2048 + wave * 512]);
        gload_lds16(bgp0, &Bs[buf][wave * 512]);
        gload_lds16(bgp1, &Bs[buf][2048 + wave * 512]);
        agp0 += 32; agp1 += 32; bgp0 += 32; bgp1 += 32;
    };

    stage(0);
    const int NIT = K >> 5;
    for (int it = 0; it < NIT; ++it) {
        const int cur = it & 1;
        __syncthreads();
        if (it + 1 < NIT) stage(cur ^ 1);
        bf16x8_t xf[4], wf[4];
#pragma unroll
        for (int bb = 0; bb < 4; ++bb)
            xf[bb] = *(const bf16x8_t*)&As[cur][(wm + bb * 16 + m16) * 32 + g4 * 8];
#pragma unroll
        for (int a = 0; a < 4; ++a)
            wf[a] = *(const bf16x8_t*)&Bs[cur][(wn + a * 16 + m16) * 32 + g4 * 8];
#pragma unroll
        for (int a = 0; a < 4; ++a)
#pragma unroll
            for (int bb = 0; bb < 4; ++bb)
                acc[a][bb] = __builtin_amdgcn_mfma_f32_16x16x32_bf16(wf[a], xf[bb], acc[a][bb], 0, 0, 0);
    }

#pragma unroll
    for (int a = 0; a < 4; ++a) {
        const int cb = n0 + wn + a * 16 + g4 * 4;
        const float4 bv4 = *(const float4*)(bias + cb);
#pragma unroll
        for (int bb = 0; bb < 4; ++bb) {
            const int r = m0 + wm + bb * 16 + m16;
            if (r < M) {
                const size_t idx = (size_t)r * N + cb;
                const float v0 = acc[a][bb][0] + bv4.x;
                const float v1 = acc[a][bb][1] + bv4.y;
                const float v2 = acc[a][bb][2] + bv4.z;
                const float v3 = acc[a][bb][3] + bv4.w;
                if constexpr (MODE == 0) {
                    ushort4 o = {f2bf(v0), f2bf(v1), f2bf(v2), f2bf(v3)};
                    *(ushort4*)(outp + idx) = o;
                } else {
                    ushort4 o = {f2bf(gelu_f(v0)), f2bf(gelu_f(v1)),
                                 f2bf(gelu_f(v2)), f2bf(gelu_f(v3))};
                    *(ushort4*)(outp + idx) = o;
                }
            }
        }
    }
}

// ---------------------------------------------------------------------------
// Split-K GEMM writing PRIVATE bf16 partial buffers (no atomics).
// blockIdx.z selects source pair: z < zsplit -> (A1,W1), else (A2,W2);
// k-offset = (z % zsplit) * Kc.  Partial z goes to parts + z*M*N.
// Weights pre-scaled (gamma folded), biases handled in the reduce pass.
// ---------------------------------------------------------------------------
__global__ __launch_bounds__(256) void gemm_splitk_kernel(
        const unsigned short* __restrict__ A1,
        const unsigned short* __restrict__ W1,
        const unsigned short* __restrict__ A2,
        const unsigned short* __restrict__ W2,
        unsigned short* __restrict__ parts,
        int M, int N, int KA, int Kc, int zsplit) {
    __shared__ unsigned short As[2][128 * 32];
    __shared__ unsigned short Bs[2][128 * 32];
    const int tid  = threadIdx.x;
    const int lane = tid & 63;
    const int wave = tid >> 6;
    const int m16  = lane & 15;
    const int g4   = lane >> 4;
    const int n0 = blockIdx.x * 128;
    const int m0 = blockIdx.y * 128;
    const int z  = blockIdx.z;
    const int wm = (wave >> 1) * 64;
    const int wn = (wave & 1) * 64;

    const unsigned short* A = (z < zsplit) ? A1 : A2;
    const unsigned short* W = (z < zsplit) ? W1 : W2;
    const int k0 = (z % zsplit) * Kc;

    const int r0  = tid >> 2;
    const int cc0 = (tid & 3) * 8;
    int am0 = m0 + r0;       if (am0 > M - 1) am0 = M - 1;
    int am1 = m0 + r0 + 64;  if (am1 > M - 1) am1 = M - 1;
    const unsigned short* agp0 = A + (size_t)am0 * KA + k0 + cc0;
    const unsigned short* agp1 = A + (size_t)am1 * KA + k0 + cc0;
    const unsigned short* bgp0 = W + (size_t)(n0 + r0) * KA + k0 + cc0;
    const unsigned short* bgp1 = W + (size_t)(n0 + r0 + 64) * KA + k0 + cc0;

    f32x4_t acc[4][4];
#pragma unroll
    for (int a = 0; a < 4; ++a)
#pragma unroll
        for (int bb = 0; bb < 4; ++bb) acc[a][bb] = zero4();

    auto stage = [&](int buf) {
        gload_lds16(agp0, &As[buf][wave * 512]);
        gload_lds16(agp1, &As[buf][2048 + wave * 512]);
        gload_lds16(bgp0, &Bs[buf][wave * 512]);
        gload_lds16(bgp1, &Bs[buf][2048 + wave * 512]);
        agp0 += 32; agp1 += 32; bgp0 += 32; bgp1 += 32;
    };

    stage(0);
    const int NIT = Kc >> 5;
    for (int it = 0; it < NIT; ++it) {
        const int cur = it & 1;
        __syncthreads();
        if (it + 1 < NIT) stage(cur ^ 1);
        bf16x8_t xf[4], wf[4];
#pragma unroll
        for (int bb = 0; bb < 4; ++bb)
            xf[bb] = *(const bf16x8_t*)&As[cur][(wm + bb * 16 + m16) * 32 + g4 * 8];
#pragma unroll
        for (int a = 0; a < 4; ++a)
            wf[a] = *(const bf16x8_t*)&Bs[cur][(wn + a * 16 + m16) * 32 + g4 * 8];
#pragma unroll
        for (int a = 0; a < 4; ++a)
#pragma unroll
            for (int bb = 0; bb < 4; ++bb)
                acc[a][bb] = __builtin_amdgcn_mfma_f32_16x16x32_bf16(wf[a], xf[bb], acc[a][bb], 0, 0, 0);
    }

    unsigned short* pz = parts + (size_t)z * M * N;
#pragma unroll
    for (int a = 0; a < 4; ++a) {
        const int cb = n0 + wn + a * 16 + g4 * 4;
#pragma unroll
        for (int bb = 0; bb < 4; ++bb) {
            const int r = m0 + wm + bb * 16 + m16;
            if (r < M) {
                const size_t idx = (size_t)r * N + cb;
                ushort4 o = {f2bf(acc[a][bb][0]), f2bf(acc[a][bb][1]),
                             f2bf(acc[a][bb][2]), f2bf(acc[a][bb][3])};
                *(ushort4*)(pz + idx) = o;
            }
        }
    }
}

// ---------------------------------------------------------------------------
// Split-K reduce: out[i] = resid[i] + bias[i%N] + sum_z parts[z][i]  (fp32 out)
// 4 elems/thread, NP partials.
// ---------------------------------------------------------------------------
template <int NP>
__global__ __launch_bounds__(256) void reduce_kernel(
        const unsigned short* __restrict__ parts,
        const float* __restrict__ resid,
        const float* __restrict__ bias,
        float* __restrict__ out, int MN, int N4mask) {
    int i = blockIdx.x * 256 + threadIdx.x;        // uint4 index
    if (i * 4 >= MN) return;
    float4 res = ((const float4*)resid)[i];
    float4 bv  = *(const float4*)(bias + (i & N4mask) * 4);
    float4 o = {res.x + bv.x, res.y + bv.y, res.z + bv.z, res.w + bv.w};
#pragma unroll
    for (int z = 0; z < NP; ++z) {
        ushort4 u = ((const ushort4*)(parts + (size_t)z * MN))[i];
        o.x += bf2f(u.x); o.y += bf2f(u.y); o.z += bf2f(u.z); o.w += bf2f(u.w);
    }
    ((float4*)out)[i] = o;
}

// ---------------------------------------------------------------------------
// V^T pre-transpose with baked PV key-permutation.
// ---------------------------------------------------------------------------
__global__ __launch_bounds__(256) void vtrans_kernel(const unsigned short* __restrict__ qkv,
                                                     unsigned short* __restrict__ vt) {
    __shared__ unsigned short Vs[64 * 64];
    const int stile = blockIdx.x;   // 0..17
    const int bh = blockIdx.y;
    const int b = bh >> 4, h = bh & 15;
    const int tid = threadIdx.x;
#pragma unroll
    for (int j = 0; j < 2; ++j) {
        int c = j * 256 + tid;
        int r = c >> 3, d8 = (c & 7) * 8;
        int s = stile * 64 + r;
        uint4 v = {0u, 0u, 0u, 0u};
        if (s < Sv) v = *(const uint4*)(qkv + ((size_t)(b * Sv + s) * 3 + 2) * Cv + h * 64 + d8);
        *(uint4*)&Vs[r * 64 + d8] = v;
    }
    __syncthreads();
    const int d  = tid >> 2;
    const int p0 = (tid & 3) * 16;
    unsigned short tmp[16];
#pragma unroll
    for (int e = 0; e < 16; ++e) {
        int p = p0 + e;
        int s_local = (p & 32) + 16 * ((p >> 2) & 1) + 4 * ((p & 31) >> 3) + (p & 3);
        tmp[e] = Vs[s_local * 64 + d];
    }
    unsigned short* dst = vt + ((size_t)bh * 64 + d) * SPADv + stile * 64 + p0;
    *(uint4*)dst       = *(const uint4*)&tmp[0];
    *(uint4*)(dst + 8) = *(const uint4*)&tmp[8];
}

// ---------------------------------------------------------------------------
// Flash attention, S^T formulation.
// ---------------------------------------------------------------------------
__global__ __launch_bounds__(256) void attn_kernel(const unsigned short* __restrict__ qkv,
                                                   const unsigned short* __restrict__ vt,
                                                   unsigned short* __restrict__ o) {
    __shared__ unsigned short Qs[64 * 64];
    __shared__ unsigned short Ks[2][64 * 64];
    __shared__ unsigned short Vts[2][64 * 64];

    const int tid  = threadIdx.x;
    const int lane = tid & 63;
    const int wave = tid >> 6;
    const int m16  = lane & 15;
    const int g4   = lane >> 4;
    const int qt = blockIdx.x;
    const int bh = blockIdx.y;
    const int b = bh >> 4, h = bh & 15;

    const int lr = lane >> 3;
    const int csw = ((lane & 7) ^ lr) * 8;
    const int sw7 = m16 & 7;

#pragma unroll
    for (int j = 0; j < 2; ++j) {
        int r = wave * 16 + j * 8 + lr;
        int s = Iv + qt * 64 + r;
        gload_lds16(qkv + ((size_t)(b * Sv + s) * 3) * Cv + h * 64 + csw,
                    &Qs[(wave * 16 + j * 8) * 64]);
    }

    auto stage_kv = [&](int st, int buf) {
#pragma unroll
        for (int j = 0; j < 2; ++j) {
            int r = wave * 16 + j * 8 + lr;
            int s = st * 64 + r; if (s > Sv - 1) s = Sv - 1;
            gload_lds16(qkv + ((size_t)(b * Sv + s) * 3 + 1) * Cv + h * 64 + csw,
                        &Ks[buf][(wave * 16 + j * 8) * 64]);
            gload_lds16(vt + ((size_t)bh * 64 + r) * SPADv + st * 64 + csw,
                        &Vts[buf][(wave * 16 + j * 8) * 64]);
        }
    };

    f32x4_t oacc[4];
#pragma unroll
    for (int dt = 0; dt < 4; ++dt) oacc[dt] = zero4();
    float m_run = -1e30f, l_run = 0.f;

    stage_kv(0, 0);
    __syncthreads();

    const bf16x8_t qf0 = *(const bf16x8_t*)&Qs[(wave * 16 + m16) * 64 + ((g4 ^ sw7) * 8)];
    const bf16x8_t qf1 = *(const bf16x8_t*)&Qs[(wave * 16 + m16) * 64 + (((4 + g4) ^ sw7) * 8)];

    const int NT = (Sv + 63) / 64;   // 18
    for (int st = 0; st < NT; ++st) {
        const int cur = st & 1;
        if (st + 1 < NT) stage_kv(st + 1, cur ^ 1);

        f32x4_t sc[4];
#pragma unroll
        for (int kt = 0; kt < 4; ++kt) {
            bf16x8_t k0 = *(const bf16x8_t*)&Ks[cur][(kt * 16 + m16) * 64 + ((g4 ^ sw7) * 8)];
            bf16x8_t k1 = *(const bf16x8_t*)&Ks[cur][(kt * 16 + m16) * 64 + (((4 + g4) ^ sw7) * 8)];
            f32x4_t z = zero4();
            z = __builtin_amdgcn_mfma_f32_16x16x32_bf16(k0, qf0, z, 0, 0, 0);
            z = __builtin_amdgcn_mfma_f32_16x16x32_bf16(k1, qf1, z, 0, 0, 0);
            sc[kt] = z;
        }

        float mx = -1e30f;
#pragma unroll
        for (int kt = 0; kt < 4; ++kt)
#pragma unroll
            for (int r = 0; r < 4; ++r) {
                int key = st * 64 + kt * 16 + g4 * 4 + r;
                float v = sc[kt][r] * 0.125f;
                v = (key < Sv) ? v : -1e30f;
                sc[kt][r] = v;
                mx = fmaxf(mx, v);
            }
        mx = fmaxf(mx, __shfl_xor(mx, 16));
        mx = fmaxf(mx, __shfl_xor(mx, 32));
        const float mnew  = fmaxf(m_run, mx);
        const float alpha = __expf(m_run - mnew);
        m_run = mnew;
        float sum = 0.f;
#pragma unroll
        for (int kt = 0; kt < 4; ++kt)
#pragma unroll
            for (int r = 0; r < 4; ++r) {
                float p = __expf(sc[kt][r] - mnew);
                sc[kt][r] = p;
                sum += p;
            }
        sum += __shfl_xor(sum, 16);
        sum += __shfl_xor(sum, 32);
        l_run = l_run * alpha + sum;
#pragma unroll
        for (int dt = 0; dt < 4; ++dt) oacc[dt] *= alpha;

        us8_t pu0, pu1;
#pragma unroll
        for (int j = 0; j < 8; ++j) {
            pu0[j] = f2bf(sc[(j >> 2)][j & 3]);
            pu1[j] = f2bf(sc[2 + (j >> 2)][j & 3]);
        }
        const bf16x8_t pf0 = __builtin_bit_cast(bf16x8_t, pu0);
        const bf16x8_t pf1 = __builtin_bit_cast(bf16x8_t, pu1);

#pragma unroll
        for (int dt = 0; dt < 4; ++dt) {
            bf16x8_t v0 = *(const bf16x8_t*)&Vts[cur][(dt * 16 + m16) * 64 + ((g4 ^ sw7) * 8)];
            bf16x8_t v1 = *(const bf16x8_t*)&Vts[cur][(dt * 16 + m16) * 64 + (((4 + g4) ^ sw7) * 8)];
            oacc[dt] = __builtin_amdgcn_mfma_f32_16x16x32_bf16(v0, pf0, oacc[dt], 0, 0, 0);
            oacc[dt] = __builtin_amdgcn_mfma_f32_16x16x32_bf16(v1, pf1, oacc[dt], 0, 0, 0);
        }
        __syncthreads();
    }

    const float inv = 1.0f / l_run;
    const int q = qt * 64 + wave * 16 + m16;
    const size_t row = (size_t)(b * Nv + q) * Cv + h * 64;
#pragma unroll
    for (int dt = 0; dt < 4; ++dt) {
        ushort4 o4 = {f2bf(oacc[dt][0] * inv), f2bf(oacc[dt][1] * inv),
                      f2bf(oacc[dt][2] * inv), f2bf(oacc[dt][3] * inv)};
        *(ushort4*)&o[row + dt * 16 + g4 * 4] = o4;
    }
}

// ---------------------------------------------------------------------------
// Launcher
// ---------------------------------------------------------------------------
extern "C" void kernel_launch(void* const* d_in, const int* in_sizes, int n_in,
                              void* d_out, int out_size, void* d_ws, size_t ws_size,
                              hipStream_t stream) {
    (void)in_sizes; (void)n_in; (void)out_size; (void)ws_size;
    const float* x       = (const float*)d_in[0];
    const float* instr   = (const float*)d_in[1];
    const float* norm1_w = (const float*)d_in[2];
    const float* norm1_b = (const float*)d_in[3];
    const float* qkv_w   = (const float*)d_in[4];
    const float* q_bias  = (const float*)d_in[5];
    const float* v_bias  = (const float*)d_in[6];
    const float* proj_w  = (const float*)d_in[7];
    const float* proj_b  = (const float*)d_in[8];
    const float* gamma_1 = (const float*)d_in[9];
    const float* gamma_2 = (const float*)d_in[10];
    const float* norm2_w = (const float*)d_in[11];
    const float* norm2_b = (const float*)d_in[12];
    const float* fc1_w   = (const float*)d_in[13];
    const float* fc1_b   = (const float*)d_in[14];
    const float* fc2_w   = (const float*)d_in[15];
    const float* fc2_b   = (const float*)d_in[16];
    const float* pfc1_w  = (const float*)d_in[17];
    const float* pfc1_b  = (const float*)d_in[18];
    const float* pfc2_w  = (const float*)d_in[19];
    const float* pfc2_b  = (const float*)d_in[20];
    const float* gate    = (const float*)d_in[21];
    const float* ir_ln_w = (const float*)d_in[22];
    const float* ir_ln_b = (const float*)d_in[23];
    const float* ir_l1_w = (const float*)d_in[24];
    const float* ir_l1_b = (const float*)d_in[25];
    const float* ir_l2_w = (const float*)d_in[26];
    const float* ir_l2_b = (const float*)d_in[27];
    float* out = (float*)d_out;

    char* ws = (char*)d_ws;
    size_t off = 0;
    auto alloc = [&](size_t bytes) -> char* {
        char* p = ws + off;
        off += (bytes + 255) & ~(size_t)255;
        return p;
    };
    unsigned short* w_qkv  = (unsigned short*)alloc((size_t)3 * Cv * Cv * 2);
    unsigned short* w_proj = (unsigned short*)alloc((size_t)Cv * Cv * 2);   // *g1
    unsigned short* w_fc1  = (unsigned short*)alloc((size_t)HIDv * Cv * 2);
    unsigned short* w_fc2  = (unsigned short*)alloc((size_t)Cv * HIDv * 2); // *g2
    unsigned short* w_pfc1 = (unsigned short*)alloc((size_t)HIDv * Cv * 2);
    unsigned short* w_pfc2 = (unsigned short*)alloc((size_t)Cv * HIDv * 2); // *gate
    unsigned short* w_ir1  = (unsigned short*)alloc((size_t)Cv * IDv * 2);
    unsigned short* w_ir2  = (unsigned short*)alloc((size_t)Cv * Cv * 2);
    float*          qkvb   = (float*)alloc((size_t)3 * Cv * 4);
    float*          bfuse  = (float*)alloc((size_t)Cv * 4);
    float*          projb  = (float*)alloc((size_t)Cv * 4);
    unsigned short* irln   = (unsigned short*)alloc((size_t)BIv * IDv * 2);
    unsigned short* h1     = (unsigned short*)alloc((size_t)BIv * Cv * 2);
    unsigned short* kvtmp  = (unsigned short*)alloc((size_t)BIv * Cv * 2);
    unsigned short* cat    = (unsigned short*)alloc((size_t)BSv * Cv * 2);      // 9.0 MB
    unsigned short* qkvbuf = (unsigned short*)alloc((size_t)BSv * 3 * Cv * 2);  // 27.1 MB
    unsigned short* obuf   = (unsigned short*)alloc((size_t)BNv * Cv * 2);
    float*          x1     = (float*)alloc((size_t)BNv * Cv * 4);
    unsigned short* ybuf   = (unsigned short*)alloc((size_t)BNv * Cv * 2);
    unsigned short* gbuf1  = (unsigned short*)alloc((size_t)BNv * HIDv * 2);    // 33.6 MB
    unsigned short* fpart  = (unsigned short*)alloc((size_t)4 * BNv * Cv * 2);  // 33.6 MB
    unsigned short* vt     = gbuf1;   // vt dead before fc1 writes gbuf1
    // ppart (proj partials, 4x8.4 MB) aliases cat+qkvbuf (dead after attn);
    // gbuf2 (pfc1 out) aliases the same region (ppart dead after reduce).
    unsigned short* ppart  = cat;
    unsigned short* gbuf2  = cat;

    cvt8_kernel<<<22272, 256, 0, stream>>>(qkv_w, proj_w, fc1_w, fc2_w, pfc1_w, pfc2_w,
                                           ir_l1_w, ir_l2_w,
                                           w_qkv, w_proj, w_fc1, w_fc2, w_pfc1, w_pfc2,
                                           w_ir1, w_ir2,
                                           gamma_1, gamma_2, gate);

    bias_prep_kernel<<<20, 256, 0, stream>>>(q_bias, v_bias, fc2_b, pfc2_b, proj_b,
                                             gamma_1, gamma_2, gate,
                                             qkvb, bfuse, projb);

    // instruct branch: LN -> Linear+GELU -> Linear
    ln_kernel<<<BIv, 256, 0, stream>>>(instr, ir_ln_w, ir_ln_b, irln,
                                       IDv, 1.0f / IDv, 1 << 28, 0, 0);
    // LN1 writes directly into cat rows b*S + I + n
    ln_kernel<<<BNv, 256, 0, stream>>>(x, norm1_w, norm1_b, cat,
                                       Cv, 1.0f / Cv, Nv, Sv, Iv);
    gemm_bf16_kernel<1><<<dim3(Cv / 128, (BIv + 127) / 128), 256, 0, stream>>>(
        irln, w_ir1, ir_l1_b, h1, BIv, Cv, IDv);
    gemm_bf16_kernel<0><<<dim3(Cv / 128, (BIv + 127) / 128), 256, 0, stream>>>(
        h1, w_ir2, ir_l2_b, kvtmp, BIv, Cv, Cv);
    scatter_kv_kernel<<<BIv, 256, 0, stream>>>(kvtmp, cat);

    // QKV projection over cat [BS, C] -> [BS, 3C]
    gemm_bf16_kernel<0><<<dim3(3 * Cv / 128, (BSv + 127) / 128), 256, 0, stream>>>(
        cat, w_qkv, qkvb, qkvbuf, BSv, 3 * Cv, Cv);

    // V^T pre-transpose (permuted), then attention
    vtrans_kernel<<<dim3(18, Bv * Hv), 256, 0, stream>>>(qkvbuf, vt);
    attn_kernel<<<dim3(Nv / 64, Bv * Hv), 256, 0, stream>>>(qkvbuf, vt, obuf);

    // proj split-K=4 (bf16 partials), reduce: x1 = x + g1*proj_b + sum(parts)
    gemm_splitk_kernel<<<dim3(Cv / 128, BNv / 128, 4), 256, 0, stream>>>(
        obuf, w_proj, obuf, w_proj, ppart, BNv, Cv, Cv, Cv / 4, 4);
    reduce_kernel<4><<<(BNv * Cv / 4 + 255) / 256, 256, 0, stream>>>(
        ppart, x, projb, x1, BNv * Cv, Cv / 4 - 1);

    // LN2
    ln_kernel<<<BNv, 256, 0, stream>>>(x1, norm2_w, norm2_b, ybuf,
                                       Cv, 1.0f / Cv, 1 << 28, 0, 0);

    // fc1 / pfc1 (separate, 1024 blocks each)
    gemm_bf16_kernel<1><<<dim3(HIDv / 128, BNv / 128), 256, 0, stream>>>(
        ybuf, w_fc1, fc1_b, gbuf1, BNv, HIDv, Cv);
    gemm_bf16_kernel<1><<<dim3(HIDv / 128, BNv / 128), 256, 0, stream>>>(
        ybuf, w_pfc1, pfc1_b, gbuf2, BNv, HIDv, Cv);

    // fc2 + pfc2 as one split-K dispatch (z=0,1 -> fc2 halves; z=2,3 -> pfc2)
    gemm_splitk_kernel<<<dim3(Cv / 128, BNv / 128, 4), 256, 0, stream>>>(
        gbuf1, w_fc2, gbuf2, w_pfc2, fpart, BNv, Cv, HIDv, HIDv / 2, 2);
    // out = x1 + (g2*fc2_b + gate*pfc2_b) + sum(parts)
    reduce_kernel<4><<<(BNv * Cv / 4 + 255) / 256, 256, 0, stream>>>(
        fpart, x1, bfuse, out, BNv * Cv, Cv / 4 - 1);
}